// Round 8
// baseline (207.111 us; speedup 1.0000x reference)
//
#include <hip/hip_runtime.h>
#include <hip/hip_bf16.h>

// Fused triplane sample + reshape-semantics MLP (32->128->128->4, ReLU),
// perm [1,2,3,0] baked. Operand-swapped MFMAs (r3), chunked 32-ch staging
// (r4), coalesced 4-lane/texel gather (r6), clamp-free axis math (r7).
// r8: (a) hbq XOR-swizzle -- 8B-block index ^= (l15&3)<<1 on BOTH write and
//     read (self-inverse), breaking the (l15,l15+8) bank degeneracy of the
//     stride-80B rows at zero extra registers;
// (b) s_setprio(1) around phase-B tile bodies (T5): blocks on one CU sit in
//     different phases (A=gather vs B=MFMA), so MFMA waves win arbitration;
// (c) prep kernels merged into one dispatch.
// Math, accumulation order, and output layout identical to r7.

#define C_ 32
#define HW_ (128 * 128)
#define HQS 40                /* hbq row stride in shorts (80 B, 16B-aligned) */

typedef short s8v __attribute__((ext_vector_type(8)));
typedef float f4v __attribute__((ext_vector_type(4)));
typedef unsigned int u4v __attribute__((ext_vector_type(4)));
typedef unsigned int u2v __attribute__((ext_vector_type(2)));

__device__ __attribute__((aligned(64))) unsigned short g_planes[3 * HW_ * C_]; // (3,H,W,C) bf16
__device__ __attribute__((aligned(16))) unsigned short g_w0[128 * 32];
__device__ __attribute__((aligned(16))) unsigned short g_w1[128 * 128];
__device__ __attribute__((aligned(16))) unsigned short g_w2[16 * 128];  // perm-baked, padded
__device__ __attribute__((aligned(16))) float g_b0[128];
__device__ __attribute__((aligned(16))) float g_b1[128];
__device__ __attribute__((aligned(16))) float g_b2p[16];

template <typename TO, typename FROM>
static __device__ __forceinline__ TO bitc(FROM f) {
    union { FROM a; TO b; } u; u.a = f; return u.b;
}

// MFMA operand-type shim (v8i16 vs v8bf16 builtin signature) -- proven.
template <typename V>
static __device__ __forceinline__ auto mfma_k32(V a, V b, f4v c, int)
    -> decltype(__builtin_amdgcn_mfma_f32_16x16x32_bf16(a, b, c, 0, 0, 0)) {
    return __builtin_amdgcn_mfma_f32_16x16x32_bf16(a, b, c, 0, 0, 0);
}
template <typename V>
static __device__ __forceinline__ f4v mfma_k32(V a, V b, f4v c, long) {
    typedef __bf16 b8v __attribute__((ext_vector_type(8)));
    return __builtin_amdgcn_mfma_f32_16x16x32_bf16(bitc<b8v>(a), bitc<b8v>(b), c, 0, 0, 0);
}
static __device__ __forceinline__ f4v MFMA(s8v a, s8v b, f4v c) {
    return mfma_k32(a, b, c, 0);
}

__device__ __forceinline__ unsigned short f2bf(float f) {
    union { float f; unsigned int i; } v; v.f = f;
    unsigned int r = v.i + 0x7FFFu + ((v.i >> 16) & 1u);
    return (unsigned short)(r >> 16);
}

// relu + pack 2 floats -> 1 u32 of 2 bf16 via v_cvt_pk_bf16_f32 (no builtin
// on gfx950 -- inline asm per guide T12)
static __device__ __forceinline__ unsigned int relu_pk(float a, float b) {
    float x = a > 0.0f ? a : 0.0f;
    float y = b > 0.0f ? b : 0.0f;
    unsigned int r;
    asm("v_cvt_pk_bf16_f32 %0, %1, %2" : "=v"(r) : "v"(x), "v"(y));
    return r;
}
static __device__ __forceinline__ unsigned int cvt_pk(float a, float b) {
    unsigned int r;
    asm("v_cvt_pk_bf16_f32 %0, %1, %2" : "=v"(r) : "v"(a), "v"(b));
    return r;
}

// ---- merged prep: planes transpose (blocks 0..767) + weights (768..831) ----
__global__ __launch_bounds__(256) void prep_all_k(const float* __restrict__ tp,
                                                  const float* __restrict__ w0,
                                                  const float* __restrict__ b0,
                                                  const float* __restrict__ w1,
                                                  const float* __restrict__ b1,
                                                  const float* __restrict__ w2,
                                                  const float* __restrict__ b2) {
    __shared__ float buf[32][65];
    const int tid = threadIdx.x;
    const int bid = blockIdx.x;
    if (bid < 768) {
        const int pl  = bid >> 8;            // plane 0..2
        const int xy0 = (bid & 255) << 6;    // 64-texel chunk
#pragma unroll
        for (int i = 0; i < 8; ++i) {
            int idx = i * 256 + tid;
            int c = idx >> 6, x = idx & 63;                   // coalesced read
            buf[c][x] = tp[(pl * C_ + c) * HW_ + xy0 + x];
        }
        __syncthreads();
#pragma unroll
        for (int i = 0; i < 8; ++i) {
            int idx = i * 256 + tid;
            int x = idx >> 5, c = idx & 31;                   // coalesced write
            g_planes[(pl * HW_ + xy0 + x) * C_ + c] = f2bf(buf[c][x]);
        }
    } else {
        int i = (bid - 768) * 256 + tid;     // 16384 threads
        if (i < 128 * 32)  g_w0[i] = f2bf(w0[i]);
        if (i < 128 * 128) g_w1[i] = f2bf(w1[i]);
        if (i < 16 * 128) {
            int n = i >> 7, k = i & 127;
            g_w2[i] = f2bf(n < 4 ? w2[((n + 1) & 3) * 128 + k] : 0.0f);
        }
        if (i < 128) { g_b0[i] = b0[i]; g_b1[i] = b1[i]; }
        if (i < 16)  g_b2p[i] = (i < 4) ? b2[(i + 1) & 3] : 0.0f;
    }
}

// ---- clamp-free bilinear helpers -------------------------------------------
static __device__ __forceinline__ void corner8(const unsigned short* __restrict__ rp,
                                               float w, float* facc) {
    const u4v dw = *(const u4v*)rp;
#pragma unroll
    for (int jj = 0; jj < 4; ++jj) {
        facc[2 * jj]     += w * __uint_as_float(dw[jj] << 16);
        facc[2 * jj + 1] += w * __uint_as_float(dw[jj] & 0xFFFF0000u);
    }
}
static __device__ __forceinline__ void plane8(const unsigned short* __restrict__ pb,
                                              int ia, int ib, float wa, float wb,
                                              float* facc) {
    const unsigned short* r0 = pb + (ib * 128 + ia) * C_;
    const unsigned short* r1 = r0 + 128 * C_;
    const float wa0 = 1.0f - wa, wb0 = 1.0f - wb;
    corner8(r0,      wa0 * wb0, facc);   // same order as reference
    corner8(r0 + C_, wa  * wb0, facc);
    corner8(r1,      wa0 * wb,  facc);
    corner8(r1 + C_, wa  * wb,  facc);
}

// ---- fused kernel -----------------------------------------------------------
__global__ __launch_bounds__(256) void fused_k(const float* __restrict__ coords,
                                               float* __restrict__ out) {
    // S[32][512] bf16 (32768 B) + 4 per-wave chunk bufs 16*HQS shorts (5120 B)
    // + bias table (1024 B) = 38912 B.
    __shared__ __attribute__((aligned(16))) unsigned short smem[16384 + 4 * 16 * HQS];
    __shared__ __attribute__((aligned(16))) float lds_bias[256];   // b0[128], b1[128]
    const int tid  = threadIdx.x;             // 0..255
    const int wave = tid >> 6;                // 0..3
    const int lane = tid & 63;
    const int l15  = lane & 15;
    const int quad = lane >> 4;
    const int ch8  = quad * 8;

    const int wg = blockIdx.x;                // 0..2047
    const int b  = wg >> 9;                   // batch
    const int nb = wg & 511;                  // 512-point block within batch
    const int n0 = nb << 9;

    if (tid < 128) { lds_bias[tid] = g_b0[tid]; lds_bias[128 + tid] = g_b1[tid]; }

    // ---- phase A: coalesced gather remap (lane = point*4 + quarter) --------
    {
        const int qa  = lane & 3;             // channel quarter 0..3
        const int p15 = lane >> 2;            // point-within-group 0..15
        const unsigned short* pb0 = g_planes + 0 * (HW_ * C_) + qa * 8;
        const unsigned short* pb1 = g_planes + 1 * (HW_ * C_) + qa * 8;
        const unsigned short* pb2 = g_planes + 2 * (HW_ * C_) + qa * 8;
#pragma unroll 1
        for (int s = 0; s < 8; ++s) {
            const int nl = s * 64 + wave * 16 + p15;   // 0..511
            const float* cp = coords + (size_t)(b * 262144 + n0 + nl) * 3;
            const float gx = cp[0], gy = cp[1], gz = cp[2];

            // per-AXIS math (clamp-free: base index <=126; inputs in [-1,1])
            float fx = (gx + 1.0f) * 63.5f;
            float fy = (gy + 1.0f) * 63.5f;
            float fz = (gz + 1.0f) * 63.5f;
            float xf = fminf(floorf(fx), 126.0f);
            float yf = fminf(floorf(fy), 126.0f);
            float zf = fminf(floorf(fz), 126.0f);
            const float wx = fx - xf, wy = fy - yf, wz = fz - zf;
            const int xi = (int)xf, yi = (int)yf, zi = (int)zf;

            float facc[8];
#pragma unroll
            for (int j = 0; j < 8; ++j) facc[j] = 0.0f;
            plane8(pb0, xi, yi, wx, wy, facc);   // feat_xy
            plane8(pb2, xi, zi, wx, wz, facc);   // feat_xz
            plane8(pb1, yi, zi, wy, wz, facc);   // feat_yz

            // XOR swizzle keeps writes conflict-free (32 banks across lanes)
            const int nlx = nl ^ (qa << 4);
#pragma unroll
            for (int j = 0; j < 4; ++j) {
                const unsigned int p = cvt_pk(facc[2 * j], facc[2 * j + 1]);
                smem[(qa * 8 + 2 * j) * 512 + nlx]     = (unsigned short)p;
                smem[(qa * 8 + 2 * j + 1) * 512 + nlx] = (unsigned short)(p >> 16);
            }
        }
    }
    __syncthreads();

    // ---- weight fragments (identical content to proven kernel) --------------
    s8v w0f[8], w1f[4][8], w2f[4];
#pragma unroll
    for (int nt = 0; nt < 8; ++nt)
        w0f[nt] = *(const s8v*)(g_w0 + (nt * 16 + l15) * 32 + ch8);
#pragma unroll
    for (int kc = 0; kc < 4; ++kc)
#pragma unroll
        for (int nt = 0; nt < 8; ++nt)
            w1f[kc][nt] = *(const s8v*)(g_w1 + (nt * 16 + l15) * 128 + kc * 32 + ch8);
#pragma unroll
    for (int kc = 0; kc < 4; ++kc)
        w2f[kc] = *(const s8v*)(g_w2 + l15 * 128 + kc * 32 + ch8);
    const f4v b2v = *(const f4v*)(g_b2p + quad * 4);   // swapped C-init, layer 3

    unsigned short* hbq = smem + 16384 + wave * (16 * HQS);  // per-wave private
    const int xw = wave << 4;                 // S read-side un-swizzle

    // hbq XOR-swizzle: 8B-block index (s*4+quad) ^= (l15&3)<<1, self-inverse.
    // Write offsets (shorts): l15*HQS + ((s^sx)<<4) + (q2<<2); read: +rq<<3.
    const int sx  = (l15 >> 1) & 1;
    const int q2  = quad ^ ((l15 & 1) << 1);
    const int wof = l15 * HQS + (q2 << 2);           // + ((s^sx)<<4) per chunk
    const int rof = l15 * HQS + ((quad ^ (l15 & 3)) << 3);

    // ---- phase B: 8 tiles per wave, operand-swapped, 32-ch chunked staging --
#pragma unroll 1
    for (int i = 0; i < 8; ++i) {
        const int ci = wave * 8 + i;          // tile 0..31
        int bo = 0;
        asm volatile("" : "+v"(bo));          // opaque 0: keep bias reads in-loop
        const float* bp = lds_bias + bo;

        const s8v a = *(const s8v*)(smem + ci * 512 + ((l15 * 32 + ch8) ^ xw));

        __builtin_amdgcn_s_setprio(1);        // T5: MFMA-phase wave wins arb

        // layer-2 accumulators, bias-initialized up front
        f4v d[8];
#pragma unroll
        for (int j = 0; j < 8; ++j)
            d[j] = *(const f4v*)(bp + 128 + j * 16 + quad * 4);

        // layer 1 -> layer 2, one 32-ch chunk (= 2 nt) at a time through hbq
#pragma unroll
        for (int kc = 0; kc < 4; ++kc) {
#pragma unroll
            for (int s = 0; s < 2; ++s) {
                const int nt = 2 * kc + s;
                const f4v bi = *(const f4v*)(bp + nt * 16 + quad * 4);
                f4v c1 = MFMA(w0f[nt], a, bi);
                u2v pk;
                pk[0] = relu_pk(c1[0], c1[1]);
                pk[1] = relu_pk(c1[2], c1[3]);
                *(u2v*)(hbq + wof + ((s ^ sx) << 4)) = pk;
            }
            const s8v a2 = *(const s8v*)(hbq + rof);  // 16B-aligned
#pragma unroll
            for (int j = 0; j < 8; ++j)
                d[j] = MFMA(w1f[kc][j], a2, d[j]);
        }

        // layer 2 -> layer 3, same chunking (kc ascending, same accum order)
        f4v o = b2v;
#pragma unroll
        for (int kc = 0; kc < 4; ++kc) {
#pragma unroll
            for (int s = 0; s < 2; ++s) {
                const int j = 2 * kc + s;
                u2v pk;
                pk[0] = relu_pk(d[j][0], d[j][1]);
                pk[1] = relu_pk(d[j][2], d[j][3]);
                *(u2v*)(hbq + wof + ((s ^ sx) << 4)) = pk;
            }
            const s8v a3 = *(const s8v*)(hbq + rof);
            o = MFMA(w2f[kc], a3, o);
        }

        __builtin_amdgcn_s_setprio(0);

        // layer 3 result: quad0 lane l15 holds comps 0..3 of its point
        if (quad == 0) {
            f4v r;
#pragma unroll
            for (int j = 0; j < 4; ++j) r[j] = o[j] > 0.0f ? o[j] : 0.0f;
            const int t = b * 16384 + ci * 512 + nb;   // global tile index
            *(f4v*)(out + (size_t)(t * 16 + l15) * 4) = r;
        }
    }
}

extern "C" void kernel_launch(void* const* d_in, const int* in_sizes, int n_in,
                              void* d_out, int out_size, void* d_ws, size_t ws_size,
                              hipStream_t stream) {
    const float* coords = (const float*)d_in[0];
    const float* tp = (const float*)d_in[1];
    const float* w0 = (const float*)d_in[2];
    const float* b0 = (const float*)d_in[3];
    const float* w1 = (const float*)d_in[4];
    const float* b1 = (const float*)d_in[5];
    const float* w2 = (const float*)d_in[6];
    const float* b2 = (const float*)d_in[7];
    float* out = (float*)d_out;               // FP32 output

    prep_all_k<<<832, 256, 0, stream>>>(tp, w0, b0, w1, b1, w2, b2);
    fused_k<<<2048, 256, 0, stream>>>(coords, out);
}

// Round 9
// 198.510 us; speedup vs baseline: 1.0433x; 1.0433x over previous
//
#include <hip/hip_runtime.h>
#include <hip/hip_bf16.h>

// Fused triplane sample + reshape-semantics MLP (32->128->128->4, ReLU),
// perm [1,2,3,0] baked. Operand-swapped MFMAs (r3), chunked 32-ch staging
// (r4), coalesced 4-lane/texel gather (r6), clamp-free axis math (r7),
// merged prep + setprio (r8). r9: REVERT the r8 hbq XOR-swizzle -- bank
// arithmetic shows r7's stride-20-word layout was already 2-way (= free,
// m136) on every access; the swizzle created real 4-way conflicts
// (counter 6.55M -> 24.4M, +7us). hbq write/read offsets restored to r7.
// Math, accumulation order, output layout identical to r7.

#define C_ 32
#define HW_ (128 * 128)
#define HQS 40                /* hbq row stride in shorts (80 B, 16B-aligned) */

typedef short s8v __attribute__((ext_vector_type(8)));
typedef float f4v __attribute__((ext_vector_type(4)));
typedef unsigned int u4v __attribute__((ext_vector_type(4)));
typedef unsigned int u2v __attribute__((ext_vector_type(2)));

__device__ __attribute__((aligned(64))) unsigned short g_planes[3 * HW_ * C_]; // (3,H,W,C) bf16
__device__ __attribute__((aligned(16))) unsigned short g_w0[128 * 32];
__device__ __attribute__((aligned(16))) unsigned short g_w1[128 * 128];
__device__ __attribute__((aligned(16))) unsigned short g_w2[16 * 128];  // perm-baked, padded
__device__ __attribute__((aligned(16))) float g_b0[128];
__device__ __attribute__((aligned(16))) float g_b1[128];
__device__ __attribute__((aligned(16))) float g_b2p[16];

template <typename TO, typename FROM>
static __device__ __forceinline__ TO bitc(FROM f) {
    union { FROM a; TO b; } u; u.a = f; return u.b;
}

// MFMA operand-type shim (v8i16 vs v8bf16 builtin signature) -- proven.
template <typename V>
static __device__ __forceinline__ auto mfma_k32(V a, V b, f4v c, int)
    -> decltype(__builtin_amdgcn_mfma_f32_16x16x32_bf16(a, b, c, 0, 0, 0)) {
    return __builtin_amdgcn_mfma_f32_16x16x32_bf16(a, b, c, 0, 0, 0);
}
template <typename V>
static __device__ __forceinline__ f4v mfma_k32(V a, V b, f4v c, long) {
    typedef __bf16 b8v __attribute__((ext_vector_type(8)));
    return __builtin_amdgcn_mfma_f32_16x16x32_bf16(bitc<b8v>(a), bitc<b8v>(b), c, 0, 0, 0);
}
static __device__ __forceinline__ f4v MFMA(s8v a, s8v b, f4v c) {
    return mfma_k32(a, b, c, 0);
}

__device__ __forceinline__ unsigned short f2bf(float f) {
    union { float f; unsigned int i; } v; v.f = f;
    unsigned int r = v.i + 0x7FFFu + ((v.i >> 16) & 1u);
    return (unsigned short)(r >> 16);
}

// relu + pack 2 floats -> 1 u32 of 2 bf16 via v_cvt_pk_bf16_f32 (no builtin
// on gfx950 -- inline asm per guide T12)
static __device__ __forceinline__ unsigned int relu_pk(float a, float b) {
    float x = a > 0.0f ? a : 0.0f;
    float y = b > 0.0f ? b : 0.0f;
    unsigned int r;
    asm("v_cvt_pk_bf16_f32 %0, %1, %2" : "=v"(r) : "v"(x), "v"(y));
    return r;
}
static __device__ __forceinline__ unsigned int cvt_pk(float a, float b) {
    unsigned int r;
    asm("v_cvt_pk_bf16_f32 %0, %1, %2" : "=v"(r) : "v"(a), "v"(b));
    return r;
}

// ---- merged prep: planes transpose (blocks 0..767) + weights (768..831) ----
__global__ __launch_bounds__(256) void prep_all_k(const float* __restrict__ tp,
                                                  const float* __restrict__ w0,
                                                  const float* __restrict__ b0,
                                                  const float* __restrict__ w1,
                                                  const float* __restrict__ b1,
                                                  const float* __restrict__ w2,
                                                  const float* __restrict__ b2) {
    __shared__ float buf[32][65];
    const int tid = threadIdx.x;
    const int bid = blockIdx.x;
    if (bid < 768) {
        const int pl  = bid >> 8;            // plane 0..2
        const int xy0 = (bid & 255) << 6;    // 64-texel chunk
#pragma unroll
        for (int i = 0; i < 8; ++i) {
            int idx = i * 256 + tid;
            int c = idx >> 6, x = idx & 63;                   // coalesced read
            buf[c][x] = tp[(pl * C_ + c) * HW_ + xy0 + x];
        }
        __syncthreads();
#pragma unroll
        for (int i = 0; i < 8; ++i) {
            int idx = i * 256 + tid;
            int x = idx >> 5, c = idx & 31;                   // coalesced write
            g_planes[(pl * HW_ + xy0 + x) * C_ + c] = f2bf(buf[c][x]);
        }
    } else {
        int i = (bid - 768) * 256 + tid;     // 16384 threads
        if (i < 128 * 32)  g_w0[i] = f2bf(w0[i]);
        if (i < 128 * 128) g_w1[i] = f2bf(w1[i]);
        if (i < 16 * 128) {
            int n = i >> 7, k = i & 127;
            g_w2[i] = f2bf(n < 4 ? w2[((n + 1) & 3) * 128 + k] : 0.0f);
        }
        if (i < 128) { g_b0[i] = b0[i]; g_b1[i] = b1[i]; }
        if (i < 16)  g_b2p[i] = (i < 4) ? b2[(i + 1) & 3] : 0.0f;
    }
}

// ---- clamp-free bilinear helpers -------------------------------------------
static __device__ __forceinline__ void corner8(const unsigned short* __restrict__ rp,
                                               float w, float* facc) {
    const u4v dw = *(const u4v*)rp;
#pragma unroll
    for (int jj = 0; jj < 4; ++jj) {
        facc[2 * jj]     += w * __uint_as_float(dw[jj] << 16);
        facc[2 * jj + 1] += w * __uint_as_float(dw[jj] & 0xFFFF0000u);
    }
}
static __device__ __forceinline__ void plane8(const unsigned short* __restrict__ pb,
                                              int ia, int ib, float wa, float wb,
                                              float* facc) {
    const unsigned short* r0 = pb + (ib * 128 + ia) * C_;
    const unsigned short* r1 = r0 + 128 * C_;
    const float wa0 = 1.0f - wa, wb0 = 1.0f - wb;
    corner8(r0,      wa0 * wb0, facc);   // same order as reference
    corner8(r0 + C_, wa  * wb0, facc);
    corner8(r1,      wa0 * wb,  facc);
    corner8(r1 + C_, wa  * wb,  facc);
}

// ---- fused kernel -----------------------------------------------------------
__global__ __launch_bounds__(256) void fused_k(const float* __restrict__ coords,
                                               float* __restrict__ out) {
    // S[32][512] bf16 (32768 B) + 4 per-wave chunk bufs 16*HQS shorts (5120 B)
    // + bias table (1024 B) = 38912 B.
    __shared__ __attribute__((aligned(16))) unsigned short smem[16384 + 4 * 16 * HQS];
    __shared__ __attribute__((aligned(16))) float lds_bias[256];   // b0[128], b1[128]
    const int tid  = threadIdx.x;             // 0..255
    const int wave = tid >> 6;                // 0..3
    const int lane = tid & 63;
    const int l15  = lane & 15;
    const int quad = lane >> 4;
    const int ch8  = quad * 8;

    const int wg = blockIdx.x;                // 0..2047
    const int b  = wg >> 9;                   // batch
    const int nb = wg & 511;                  // 512-point block within batch
    const int n0 = nb << 9;

    if (tid < 128) { lds_bias[tid] = g_b0[tid]; lds_bias[128 + tid] = g_b1[tid]; }

    // ---- phase A: coalesced gather remap (lane = point*4 + quarter) --------
    {
        const int qa  = lane & 3;             // channel quarter 0..3
        const int p15 = lane >> 2;            // point-within-group 0..15
        const unsigned short* pb0 = g_planes + 0 * (HW_ * C_) + qa * 8;
        const unsigned short* pb1 = g_planes + 1 * (HW_ * C_) + qa * 8;
        const unsigned short* pb2 = g_planes + 2 * (HW_ * C_) + qa * 8;
#pragma unroll 1
        for (int s = 0; s < 8; ++s) {
            const int nl = s * 64 + wave * 16 + p15;   // 0..511
            const float* cp = coords + (size_t)(b * 262144 + n0 + nl) * 3;
            const float gx = cp[0], gy = cp[1], gz = cp[2];

            // per-AXIS math (clamp-free: base index <=126; inputs in [-1,1])
            float fx = (gx + 1.0f) * 63.5f;
            float fy = (gy + 1.0f) * 63.5f;
            float fz = (gz + 1.0f) * 63.5f;
            float xf = fminf(floorf(fx), 126.0f);
            float yf = fminf(floorf(fy), 126.0f);
            float zf = fminf(floorf(fz), 126.0f);
            const float wx = fx - xf, wy = fy - yf, wz = fz - zf;
            const int xi = (int)xf, yi = (int)yf, zi = (int)zf;

            float facc[8];
#pragma unroll
            for (int j = 0; j < 8; ++j) facc[j] = 0.0f;
            plane8(pb0, xi, yi, wx, wy, facc);   // feat_xy
            plane8(pb2, xi, zi, wx, wz, facc);   // feat_xz
            plane8(pb1, yi, zi, wy, wz, facc);   // feat_yz

            // XOR swizzle keeps writes conflict-free (32 banks across lanes)
            const int nlx = nl ^ (qa << 4);
#pragma unroll
            for (int j = 0; j < 4; ++j) {
                const unsigned int p = cvt_pk(facc[2 * j], facc[2 * j + 1]);
                smem[(qa * 8 + 2 * j) * 512 + nlx]     = (unsigned short)p;
                smem[(qa * 8 + 2 * j + 1) * 512 + nlx] = (unsigned short)(p >> 16);
            }
        }
    }
    __syncthreads();

    // ---- weight fragments (identical content to proven kernel) --------------
    s8v w0f[8], w1f[4][8], w2f[4];
#pragma unroll
    for (int nt = 0; nt < 8; ++nt)
        w0f[nt] = *(const s8v*)(g_w0 + (nt * 16 + l15) * 32 + ch8);
#pragma unroll
    for (int kc = 0; kc < 4; ++kc)
#pragma unroll
        for (int nt = 0; nt < 8; ++nt)
            w1f[kc][nt] = *(const s8v*)(g_w1 + (nt * 16 + l15) * 128 + kc * 32 + ch8);
#pragma unroll
    for (int kc = 0; kc < 4; ++kc)
        w2f[kc] = *(const s8v*)(g_w2 + l15 * 128 + kc * 32 + ch8);
    const f4v b2v = *(const f4v*)(g_b2p + quad * 4);   // swapped C-init, layer 3

    unsigned short* hbq = smem + 16384 + wave * (16 * HQS);  // per-wave private
    const int xw = wave << 4;                 // S read-side un-swizzle

    // ---- phase B: 8 tiles per wave, operand-swapped, 32-ch chunked staging --
#pragma unroll 1
    for (int i = 0; i < 8; ++i) {
        const int ci = wave * 8 + i;          // tile 0..31
        int bo = 0;
        asm volatile("" : "+v"(bo));          // opaque 0: keep bias reads in-loop
        const float* bp = lds_bias + bo;

        const s8v a = *(const s8v*)(smem + ci * 512 + ((l15 * 32 + ch8) ^ xw));

        __builtin_amdgcn_s_setprio(1);        // T5: MFMA-phase wave wins arb

        // layer-2 accumulators, bias-initialized up front
        f4v d[8];
#pragma unroll
        for (int j = 0; j < 8; ++j)
            d[j] = *(const f4v*)(bp + 128 + j * 16 + quad * 4);

        // layer 1 -> layer 2, one 32-ch chunk (= 2 nt) at a time through hbq
#pragma unroll
        for (int kc = 0; kc < 4; ++kc) {
#pragma unroll
            for (int s = 0; s < 2; ++s) {
                const int nt = 2 * kc + s;
                const f4v bi = *(const f4v*)(bp + nt * 16 + quad * 4);
                f4v c1 = MFMA(w0f[nt], a, bi);
                u2v pk;
                pk[0] = relu_pk(c1[0], c1[1]);
                pk[1] = relu_pk(c1[2], c1[3]);
                // bytes: l15*80 + s*32 + quad*8  (2 lanes/bank = free)
                *(u2v*)(hbq + l15 * HQS + s * 16 + quad * 4) = pk;
            }
            const s8v a2 = *(const s8v*)(hbq + l15 * HQS + ch8);  // 16B-aligned
#pragma unroll
            for (int j = 0; j < 8; ++j)
                d[j] = MFMA(w1f[kc][j], a2, d[j]);
        }

        // layer 2 -> layer 3, same chunking (kc ascending, same accum order)
        f4v o = b2v;
#pragma unroll
        for (int kc = 0; kc < 4; ++kc) {
#pragma unroll
            for (int s = 0; s < 2; ++s) {
                const int j = 2 * kc + s;
                u2v pk;
                pk[0] = relu_pk(d[j][0], d[j][1]);
                pk[1] = relu_pk(d[j][2], d[j][3]);
                *(u2v*)(hbq + l15 * HQS + s * 16 + quad * 4) = pk;
            }
            const s8v a3 = *(const s8v*)(hbq + l15 * HQS + ch8);
            o = MFMA(w2f[kc], a3, o);
        }

        __builtin_amdgcn_s_setprio(0);

        // layer 3 result: quad0 lane l15 holds comps 0..3 of its point
        if (quad == 0) {
            f4v r;
#pragma unroll
            for (int j = 0; j < 4; ++j) r[j] = o[j] > 0.0f ? o[j] : 0.0f;
            const int t = b * 16384 + ci * 512 + nb;   // global tile index
            *(f4v*)(out + (size_t)(t * 16 + l15) * 4) = r;
        }
    }
}

extern "C" void kernel_launch(void* const* d_in, const int* in_sizes, int n_in,
                              void* d_out, int out_size, void* d_ws, size_t ws_size,
                              hipStream_t stream) {
    const float* coords = (const float*)d_in[0];
    const float* tp = (const float*)d_in[1];
    const float* w0 = (const float*)d_in[2];
    const float* b0 = (const float*)d_in[3];
    const float* w1 = (const float*)d_in[4];
    const float* b1 = (const float*)d_in[5];
    const float* w2 = (const float*)d_in[6];
    const float* b2 = (const float*)d_in[7];
    float* out = (float*)d_out;               // FP32 output

    prep_all_k<<<832, 256, 0, stream>>>(tp, w0, b0, w1, b1, w2, b2);
    fused_k<<<2048, 256, 0, stream>>>(coords, out);
}

// Round 11
// 195.820 us; speedup vs baseline: 1.0577x; 1.0137x over previous
//
#include <hip/hip_runtime.h>
#include <hip/hip_bf16.h>

// Fused triplane sample + reshape-semantics MLP (32->128->128->4, ReLU),
// perm [1,2,3,0] baked. Operand-swapped MFMAs (r3), chunked 32-ch staging
// (r4), coalesced 4-lane/texel gather (r6), clamp-free axis math (r7),
// merged prep + setprio (r8/r9). r10/r11: phase-A COORD PREFETCH ROTATION --
// slot s+1's coords (HBM, ~900cy) issue at the top of slot s's body, and
// the s-loop relaxes to unroll 2, so the coord latency hides under the
// previous slot's gather+fma work. Accepts VGPR 128 -> ~150 (3 waves/SIMD;
// measured effective occupancy ~6.7 waves/CU, so the cap shouldn't bind).
// Math, accumulation order, output layout identical to r9.
// (r10 bench was an infra failure -- "container failed twice" -- resubmit.)

#define C_ 32
#define HW_ (128 * 128)
#define HQS 40                /* hbq row stride in shorts (80 B, 16B-aligned) */

typedef short s8v __attribute__((ext_vector_type(8)));
typedef float f4v __attribute__((ext_vector_type(4)));
typedef unsigned int u4v __attribute__((ext_vector_type(4)));
typedef unsigned int u2v __attribute__((ext_vector_type(2)));

__device__ __attribute__((aligned(64))) unsigned short g_planes[3 * HW_ * C_]; // (3,H,W,C) bf16
__device__ __attribute__((aligned(16))) unsigned short g_w0[128 * 32];
__device__ __attribute__((aligned(16))) unsigned short g_w1[128 * 128];
__device__ __attribute__((aligned(16))) unsigned short g_w2[16 * 128];  // perm-baked, padded
__device__ __attribute__((aligned(16))) float g_b0[128];
__device__ __attribute__((aligned(16))) float g_b1[128];
__device__ __attribute__((aligned(16))) float g_b2p[16];

template <typename TO, typename FROM>
static __device__ __forceinline__ TO bitc(FROM f) {
    union { FROM a; TO b; } u; u.a = f; return u.b;
}

// MFMA operand-type shim (v8i16 vs v8bf16 builtin signature) -- proven.
template <typename V>
static __device__ __forceinline__ auto mfma_k32(V a, V b, f4v c, int)
    -> decltype(__builtin_amdgcn_mfma_f32_16x16x32_bf16(a, b, c, 0, 0, 0)) {
    return __builtin_amdgcn_mfma_f32_16x16x32_bf16(a, b, c, 0, 0, 0);
}
template <typename V>
static __device__ __forceinline__ f4v mfma_k32(V a, V b, f4v c, long) {
    typedef __bf16 b8v __attribute__((ext_vector_type(8)));
    return __builtin_amdgcn_mfma_f32_16x16x32_bf16(bitc<b8v>(a), bitc<b8v>(b), c, 0, 0, 0);
}
static __device__ __forceinline__ f4v MFMA(s8v a, s8v b, f4v c) {
    return mfma_k32(a, b, c, 0);
}

__device__ __forceinline__ unsigned short f2bf(float f) {
    union { float f; unsigned int i; } v; v.f = f;
    unsigned int r = v.i + 0x7FFFu + ((v.i >> 16) & 1u);
    return (unsigned short)(r >> 16);
}

// relu + pack 2 floats -> 1 u32 of 2 bf16 via v_cvt_pk_bf16_f32 (no builtin
// on gfx950 -- inline asm per guide T12)
static __device__ __forceinline__ unsigned int relu_pk(float a, float b) {
    float x = a > 0.0f ? a : 0.0f;
    float y = b > 0.0f ? b : 0.0f;
    unsigned int r;
    asm("v_cvt_pk_bf16_f32 %0, %1, %2" : "=v"(r) : "v"(x), "v"(y));
    return r;
}
static __device__ __forceinline__ unsigned int cvt_pk(float a, float b) {
    unsigned int r;
    asm("v_cvt_pk_bf16_f32 %0, %1, %2" : "=v"(r) : "v"(a), "v"(b));
    return r;
}

// ---- merged prep: planes transpose (blocks 0..767) + weights (768..831) ----
__global__ __launch_bounds__(256) void prep_all_k(const float* __restrict__ tp,
                                                  const float* __restrict__ w0,
                                                  const float* __restrict__ b0,
                                                  const float* __restrict__ w1,
                                                  const float* __restrict__ b1,
                                                  const float* __restrict__ w2,
                                                  const float* __restrict__ b2) {
    __shared__ float buf[32][65];
    const int tid = threadIdx.x;
    const int bid = blockIdx.x;
    if (bid < 768) {
        const int pl  = bid >> 8;            // plane 0..2
        const int xy0 = (bid & 255) << 6;    // 64-texel chunk
#pragma unroll
        for (int i = 0; i < 8; ++i) {
            int idx = i * 256 + tid;
            int c = idx >> 6, x = idx & 63;                   // coalesced read
            buf[c][x] = tp[(pl * C_ + c) * HW_ + xy0 + x];
        }
        __syncthreads();
#pragma unroll
        for (int i = 0; i < 8; ++i) {
            int idx = i * 256 + tid;
            int x = idx >> 5, c = idx & 31;                   // coalesced write
            g_planes[(pl * HW_ + xy0 + x) * C_ + c] = f2bf(buf[c][x]);
        }
    } else {
        int i = (bid - 768) * 256 + tid;     // 16384 threads
        if (i < 128 * 32)  g_w0[i] = f2bf(w0[i]);
        if (i < 128 * 128) g_w1[i] = f2bf(w1[i]);
        if (i < 16 * 128) {
            int n = i >> 7, k = i & 127;
            g_w2[i] = f2bf(n < 4 ? w2[((n + 1) & 3) * 128 + k] : 0.0f);
        }
        if (i < 128) { g_b0[i] = b0[i]; g_b1[i] = b1[i]; }
        if (i < 16)  g_b2p[i] = (i < 4) ? b2[(i + 1) & 3] : 0.0f;
    }
}

// ---- clamp-free bilinear helpers -------------------------------------------
static __device__ __forceinline__ void corner8(const unsigned short* __restrict__ rp,
                                               float w, float* facc) {
    const u4v dw = *(const u4v*)rp;
#pragma unroll
    for (int jj = 0; jj < 4; ++jj) {
        facc[2 * jj]     += w * __uint_as_float(dw[jj] << 16);
        facc[2 * jj + 1] += w * __uint_as_float(dw[jj] & 0xFFFF0000u);
    }
}
static __device__ __forceinline__ void plane8(const unsigned short* __restrict__ pb,
                                              int ia, int ib, float wa, float wb,
                                              float* facc) {
    const unsigned short* r0 = pb + (ib * 128 + ia) * C_;
    const unsigned short* r1 = r0 + 128 * C_;
    const float wa0 = 1.0f - wa, wb0 = 1.0f - wb;
    corner8(r0,      wa0 * wb0, facc);   // same order as reference
    corner8(r0 + C_, wa  * wb0, facc);
    corner8(r1,      wa0 * wb,  facc);
    corner8(r1 + C_, wa  * wb,  facc);
}

// ---- fused kernel -----------------------------------------------------------
__global__ __launch_bounds__(256) void fused_k(const float* __restrict__ coords,
                                               float* __restrict__ out) {
    // S[32][512] bf16 (32768 B) + 4 per-wave chunk bufs 16*HQS shorts (5120 B)
    // + bias table (1024 B) = 38912 B.
    __shared__ __attribute__((aligned(16))) unsigned short smem[16384 + 4 * 16 * HQS];
    __shared__ __attribute__((aligned(16))) float lds_bias[256];   // b0[128], b1[128]
    const int tid  = threadIdx.x;             // 0..255
    const int wave = tid >> 6;                // 0..3
    const int lane = tid & 63;
    const int l15  = lane & 15;
    const int quad = lane >> 4;
    const int ch8  = quad * 8;

    const int wg = blockIdx.x;                // 0..2047
    const int b  = wg >> 9;                   // batch
    const int nb = wg & 511;                  // 512-point block within batch
    const int n0 = nb << 9;

    if (tid < 128) { lds_bias[tid] = g_b0[tid]; lds_bias[128 + tid] = g_b1[tid]; }

    // ---- phase A: coalesced gather remap (lane = point*4 + quarter) --------
    {
        const int qa  = lane & 3;             // channel quarter 0..3
        const int p15 = lane >> 2;            // point-within-group 0..15
        const unsigned short* pb0 = g_planes + 0 * (HW_ * C_) + qa * 8;
        const unsigned short* pb1 = g_planes + 1 * (HW_ * C_) + qa * 8;
        const unsigned short* pb2 = g_planes + 2 * (HW_ * C_) + qa * 8;
        const float* cp0 = coords + (size_t)(b * 262144 + n0 + wave * 16 + p15) * 3;
        // coord prefetch rotation: slot s+1's coords issue before slot s's body
        float gx = cp0[0], gy = cp0[1], gz = cp0[2];
#pragma unroll 2
        for (int s = 0; s < 8; ++s) {
            float ngx, ngy, ngz;
            if (s < 7) {
                const float* cpn = cp0 + (s + 1) * 192;   // +64 points * 3
                ngx = cpn[0]; ngy = cpn[1]; ngz = cpn[2];
            }
            const int nl = s * 64 + wave * 16 + p15;      // 0..511

            // per-AXIS math (clamp-free: base index <=126; inputs in [-1,1])
            float fx = (gx + 1.0f) * 63.5f;
            float fy = (gy + 1.0f) * 63.5f;
            float fz = (gz + 1.0f) * 63.5f;
            float xf = fminf(floorf(fx), 126.0f);
            float yf = fminf(floorf(fy), 126.0f);
            float zf = fminf(floorf(fz), 126.0f);
            const float wx = fx - xf, wy = fy - yf, wz = fz - zf;
            const int xi = (int)xf, yi = (int)yf, zi = (int)zf;

            float facc[8];
#pragma unroll
            for (int j = 0; j < 8; ++j) facc[j] = 0.0f;
            plane8(pb0, xi, yi, wx, wy, facc);   // feat_xy
            plane8(pb2, xi, zi, wx, wz, facc);   // feat_xz
            plane8(pb1, yi, zi, wy, wz, facc);   // feat_yz

            // XOR swizzle keeps writes conflict-free (32 banks across lanes)
            const int nlx = nl ^ (qa << 4);
#pragma unroll
            for (int j = 0; j < 4; ++j) {
                const unsigned int p = cvt_pk(facc[2 * j], facc[2 * j + 1]);
                smem[(qa * 8 + 2 * j) * 512 + nlx]     = (unsigned short)p;
                smem[(qa * 8 + 2 * j + 1) * 512 + nlx] = (unsigned short)(p >> 16);
            }
            gx = ngx; gy = ngy; gz = ngz;
        }
    }
    __syncthreads();

    // ---- weight fragments (identical content to proven kernel) --------------
    s8v w0f[8], w1f[4][8], w2f[4];
#pragma unroll
    for (int nt = 0; nt < 8; ++nt)
        w0f[nt] = *(const s8v*)(g_w0 + (nt * 16 + l15) * 32 + ch8);
#pragma unroll
    for (int kc = 0; kc < 4; ++kc)
#pragma unroll
        for (int nt = 0; nt < 8; ++nt)
            w1f[kc][nt] = *(const s8v*)(g_w1 + (nt * 16 + l15) * 128 + kc * 32 + ch8);
#pragma unroll
    for (int kc = 0; kc < 4; ++kc)
        w2f[kc] = *(const s8v*)(g_w2 + l15 * 128 + kc * 32 + ch8);
    const f4v b2v = *(const f4v*)(g_b2p + quad * 4);   // swapped C-init, layer 3

    unsigned short* hbq = smem + 16384 + wave * (16 * HQS);  // per-wave private
    const int xw = wave << 4;                 // S read-side un-swizzle

    // ---- phase B: 8 tiles per wave, operand-swapped, 32-ch chunked staging --
#pragma unroll 1
    for (int i = 0; i < 8; ++i) {
        const int ci = wave * 8 + i;          // tile 0..31
        int bo = 0;
        asm volatile("" : "+v"(bo));          // opaque 0: keep bias reads in-loop
        const float* bp = lds_bias + bo;

        const s8v a = *(const s8v*)(smem + ci * 512 + ((l15 * 32 + ch8) ^ xw));

        __builtin_amdgcn_s_setprio(1);        // T5: MFMA-phase wave wins arb

        // layer-2 accumulators, bias-initialized up front
        f4v d[8];
#pragma unroll
        for (int j = 0; j < 8; ++j)
            d[j] = *(const f4v*)(bp + 128 + j * 16 + quad * 4);

        // layer 1 -> layer 2, one 32-ch chunk (= 2 nt) at a time through hbq
#pragma unroll
        for (int kc = 0; kc < 4; ++kc) {
#pragma unroll
            for (int s = 0; s < 2; ++s) {
                const int nt = 2 * kc + s;
                const f4v bi = *(const f4v*)(bp + nt * 16 + quad * 4);
                f4v c1 = MFMA(w0f[nt], a, bi);
                u2v pk;
                pk[0] = relu_pk(c1[0], c1[1]);
                pk[1] = relu_pk(c1[2], c1[3]);
                // bytes: l15*80 + s*32 + quad*8  (2 lanes/bank = free)
                *(u2v*)(hbq + l15 * HQS + s * 16 + quad * 4) = pk;
            }
            const s8v a2 = *(const s8v*)(hbq + l15 * HQS + ch8);  // 16B-aligned
#pragma unroll
            for (int j = 0; j < 8; ++j)
                d[j] = MFMA(w1f[kc][j], a2, d[j]);
        }

        // layer 2 -> layer 3, same chunking (kc ascending, same accum order)
        f4v o = b2v;
#pragma unroll
        for (int kc = 0; kc < 4; ++kc) {
#pragma unroll
            for (int s = 0; s < 2; ++s) {
                const int j = 2 * kc + s;
                u2v pk;
                pk[0] = relu_pk(d[j][0], d[j][1]);
                pk[1] = relu_pk(d[j][2], d[j][3]);
                *(u2v*)(hbq + l15 * HQS + s * 16 + quad * 4) = pk;
            }
            const s8v a3 = *(const s8v*)(hbq + l15 * HQS + ch8);
            o = MFMA(w2f[kc], a3, o);
        }

        __builtin_amdgcn_s_setprio(0);

        // layer 3 result: quad0 lane l15 holds comps 0..3 of its point
        if (quad == 0) {
            f4v r;
#pragma unroll
            for (int j = 0; j < 4; ++j) r[j] = o[j] > 0.0f ? o[j] : 0.0f;
            const int t = b * 16384 + ci * 512 + nb;   // global tile index
            *(f4v*)(out + (size_t)(t * 16 + l15) * 4) = r;
        }
    }
}

extern "C" void kernel_launch(void* const* d_in, const int* in_sizes, int n_in,
                              void* d_out, int out_size, void* d_ws, size_t ws_size,
                              hipStream_t stream) {
    const float* coords = (const float*)d_in[0];
    const float* tp = (const float*)d_in[1];
    const float* w0 = (const float*)d_in[2];
    const float* b0 = (const float*)d_in[3];
    const float* w1 = (const float*)d_in[4];
    const float* b1 = (const float*)d_in[5];
    const float* w2 = (const float*)d_in[6];
    const float* b2 = (const float*)d_in[7];
    float* out = (float*)d_out;               // FP32 output

    prep_all_k<<<832, 256, 0, stream>>>(tp, w0, b0, w1, b1, w2, b2);
    fused_k<<<2048, 256, 0, stream>>>(coords, out);
}